// Round 6
// baseline (459.869 us; speedup 1.0000x reference)
//
#include <hip/hip_runtime.h>
#include <math.h>

#define NUM_NODES 94
#define NP 96
#define SEQ_LEN 784
#define OUT_CLASSES 10
#define B_BLK 2
#define THREADS 384      // 48 row-pairs (q) x 8 K-chunks (kq); covers W once

#define TWO_GAMMA 0.2f
#define OM2 0.0503551324598949f          // (2*pi/28)^2
#define INV_SQRT_N 0.103142124625879f    // 1/sqrt(94)
#define KS (2.0f * INV_SQRT_N)           // folded scale (for e^(2A) form)

typedef float f2 __attribute__((ext_vector_type(2)));
typedef float f4 __attribute__((ext_vector_type(4)));

__device__ __forceinline__ float dpp_add_xor1(float x) {
    int t = __builtin_amdgcn_mov_dpp(__float_as_int(x), 0xB1, 0xF, 0xF, true);
    return x + __int_as_float(t);
}
__device__ __forceinline__ float dpp_add_xor2(float x) {
    int t = __builtin_amdgcn_mov_dpp(__float_as_int(x), 0x4E, 0xF, 0xF, true);
    return x + __int_as_float(t);
}
// ROW_HALF_MIRROR: lane i <-> 7-i within each 8-lane group.
__device__ __forceinline__ float dpp_add_mirror8(float x) {
    int t = __builtin_amdgcn_mov_dpp(__float_as_int(x), 0x141, 0xF, 0xF, true);
    return x + __int_as_float(t);
}

// NOTE: per-thread W kept at 24 floats deliberately. Rounds 2-5 showed the
// allocator refuses to hold >=48 floats across a barrier loop (remats from
// L1 / bounces through AGPRs, ~1 extra op per FMA). 24 floats + ~30 misc
// fits even the default 64-VGPR budget, so W is genuinely register-resident.
__global__ __launch_bounds__(THREADS)
void horn_kernel(
    const float* __restrict__ input,   // (1024, 784)
    const float* __restrict__ w_ih,    // (94, 1)
    const float* __restrict__ b_ih,    // (94)
    const float* __restrict__ w_hh,    // (94, 94)
    const float* __restrict__ b_hh,    // (94)
    const float* __restrict__ w_ro,    // (10, 94)
    const float* __restrict__ b_ro,    // (10)
    float* __restrict__ out)           // (1024, 10)
{
    __shared__ __align__(16) float ylds[2][B_BLK][NP];     // double-buffered y
    __shared__ __align__(16) float slds[B_BLK][SEQ_LEN];   // input rows

    const int tid = threadIdx.x;
    const int q   = tid >> 3;        // 0..47 -> rows 2q, 2q+1
    const int kq  = tid & 7;         // 0..7  -> cols 12kq..12kq+11
    const int b0  = blockIdx.x * B_BLK;

    // Prefetch both input rows (contiguous in global) as float4.
    {
        const f4* in4 = (const f4*)(input + (size_t)b0 * SEQ_LEN);
        f4* s4 = (f4*)&slds[0][0];
        #pragma unroll 1
        for (int i = tid; i < B_BLK * SEQ_LEN / 4; i += THREADS) s4[i] = in4[i];
    }
    // Zero both y buffers (2*2*96 = 384 floats = THREADS).
    ((float*)ylds)[tid] = 0.0f;

    // W block: rows 2q,2q+1, cols 12kq..12kq+11, pre-scaled by KS.
    const int row0 = 2 * q, col0 = 12 * kq;
    f2 w2[2][6];
    #pragma unroll
    for (int i = 0; i < 2; i++) {
        const int rr = row0 + i;
        #pragma unroll
        for (int c = 0; c < 12; c++) {
            const int cc = col0 + c;
            float v = (rr < NUM_NODES && cc < NUM_NODES)
                        ? w_hh[rr * NUM_NODES + cc] * KS : 0.0f;
            w2[i][c >> 1][c & 1] = v;
        }
    }

    // Mirror-symmetric state ownership: lanes kq and 7-kq own the same
    // (row, element) state so the final mirror8 add completes the 8-lane sum.
    const int s    = (kq & 3) ^ ((kq >> 2) * 3);   // 0..3
    const int rs   = s & 1;         // row select within pair
    const int es   = s >> 1;        // element select
    const int nown = row0 + rs;
    const bool writer = (kq < 4);   // kq 0..3 cover all 4 states exactly once
    const bool act    = (nown < NUM_NODES);
    const float wih   = act ? w_ih[nown] * KS : 0.0f;
    const float bias  = act ? (b_ih[nown] + b_hh[nown]) * KS : 0.0f;

    float x = 0.0f, y = 0.0f;

    __syncthreads();

    #define STEP(PB, TIDX)                                                    \
    {                                                                         \
        const f4* ya4 = (const f4*)&ylds[PB][0][col0];  /* 16B-aligned */     \
        const f4* yb4 = (const f4*)&ylds[PB][1][col0];                        \
        f2 p00 = {0.f,0.f}, p10 = {0.f,0.f};   /* rows x elem0 */             \
        f2 p01 = {0.f,0.f}, p11 = {0.f,0.f};   /* rows x elem1 */             \
        _Pragma("unroll")                                                     \
        for (int j = 0; j < 3; j++) {                                         \
            f4 A = ya4[j];                                                    \
            f4 B = yb4[j];                                                    \
            f2 alo = __builtin_shufflevector(A, A, 0, 1);                     \
            f2 ahi = __builtin_shufflevector(A, A, 2, 3);                     \
            f2 blo = __builtin_shufflevector(B, B, 0, 1);                     \
            f2 bhi = __builtin_shufflevector(B, B, 2, 3);                     \
            p00 += w2[0][2*j] * alo;  p00 += w2[0][2*j+1] * ahi;              \
            p10 += w2[1][2*j] * alo;  p10 += w2[1][2*j+1] * ahi;              \
            p01 += w2[0][2*j] * blo;  p01 += w2[0][2*j+1] * bhi;              \
            p11 += w2[1][2*j] * blo;  p11 += w2[1][2*j+1] * bhi;              \
        }                                                                     \
        float r00 = p00[0] + p00[1], r10 = p10[0] + p10[1];                   \
        float r01 = p01[0] + p01[1], r11 = p11[0] + p11[1];                   \
        r00 = dpp_add_xor1(r00); r00 = dpp_add_xor2(r00);                     \
        r10 = dpp_add_xor1(r10); r10 = dpp_add_xor2(r10);                     \
        r01 = dpp_add_xor1(r01); r01 = dpp_add_xor2(r01);                     \
        r11 = dpp_add_xor1(r11); r11 = dpp_add_xor2(r11);                     \
        float a0  = rs ? r10 : r00;            /* own row, elem 0 */          \
        float a1  = rs ? r11 : r01;            /* own row, elem 1 */          \
        float own = es ? a1 : a0;                                             \
        own = dpp_add_mirror8(own);            /* + partner half: full sum */ \
        float st   = slds[es][TIDX];                                          \
        float earg = fmaf(st, wih, bias) + own;        /* = 2A */             \
        float e    = __expf(earg);                                            \
        float accel = 0.5f - __builtin_amdgcn_rcpf(e + 1.0f); /* 0.5*tanh */  \
        accel = fmaf(-TWO_GAMMA, y, accel);                                   \
        accel = fmaf(-OM2, x, accel);                                         \
        x += y;                                /* H = 1 */                    \
        y += accel;                                                           \
        if (writer) ylds[PB ^ 1][es][nown] = y;                               \
        __syncthreads();                                                      \
    }

    for (int t = 0; t < SEQ_LEN; t += 2) {
        STEP(0, t)
        STEP(1, t + 1)
    }
    #undef STEP

    // Stash x over the dead y buffer, then project.
    if (writer) ylds[0][es][nown] = x;
    __syncthreads();

    if (tid < B_BLK * OUT_CLASSES * 4) {       // 80 threads
        const int e  = tid / 40;
        const int rm = tid % 40;
        const int c  = rm >> 2;
        const int k2 = rm & 3;                 // quad-aligned (40 = 10 quads)
        float sacc = 0.0f;
        #pragma unroll
        for (int i = 0; i < 24; i++) {
            const int j = k2 * 24 + i;
            if (j < NUM_NODES) sacc += ylds[0][e][j] * w_ro[c * NUM_NODES + j];
        }
        sacc = dpp_add_xor1(sacc);
        sacc = dpp_add_xor2(sacc);
        if (k2 == 0) out[(size_t)(b0 + e) * OUT_CLASSES + c] = sacc + b_ro[c];
    }
}

extern "C" void kernel_launch(void* const* d_in, const int* in_sizes, int n_in,
                              void* d_out, int out_size, void* d_ws, size_t ws_size,
                              hipStream_t stream) {
    const float* input = (const float*)d_in[0];
    const float* w_ih  = (const float*)d_in[1];
    const float* b_ih  = (const float*)d_in[2];
    const float* w_hh  = (const float*)d_in[3];
    const float* b_hh  = (const float*)d_in[4];
    const float* w_ro  = (const float*)d_in[5];
    const float* b_ro  = (const float*)d_in[6];
    float* out = (float*)d_out;

    const int batch = in_sizes[0] / SEQ_LEN;   // 1024
    dim3 grid(batch / B_BLK);                  // 512 blocks -> 2 per CU
    dim3 block(THREADS);                       // 384 threads = 6 waves

    hipLaunchKernelGGL(horn_kernel, grid, block, 0, stream,
                       input, w_ih, b_ih, w_hh, b_hh, w_ro, b_ro, out);
}